// Round 3
// baseline (81.927 us; speedup 1.0000x reference)
//
#include <hip/hip_runtime.h>

// BezierToImageLayer as a sparse-fill MFMA GEMM.
// result[b,i,j] = clamp(sum_k gx[k][i]*gy[k][j]) with k = 4800 splats:
// a 64x64x4800 f16 GEMM per sample. Gx/Gy are 6-sparse per column (alpha=2e-4
// -> 6-tap window, error ~2e-3 << 2e-2) and built in LDS with plain
// ds_write_b16 (each splat owns its k-column -> NO atomics).
//
// R3: back to the VERIFIED R0 envelope (grid 256 / block 256 / 64 KiB LDS /
// single kernel / direct clamped stores) after two failed occupancy
// restructures. Only change: the main loop is ROTATED into a software
// pipeline. R0 ran each chunk as a fully serial chain
// (VALU -> exp2 -> ds_write -> drain -> ds_read -> drain -> MFMA): ~5200
// cyc/chunk measured vs ~650 cyc of issue work, all latency exposed at
// 1 wave/SIMD. Now each iteration: read frags of the tile written LAST
// iteration (write latency already hidden), compute next chunk's taps into
// registers (overlaps read latency), MFMA, then zero+write next tile (its
// latency hides under the next iteration). Same-wave DS ordering (reads
// issued before aliasing writes) is the same property R0 already relies on;
// every LDS address expression is byte-identical to R0.
//
// Tile row r = image row r-2 (C rows 2..61 are the 60 output pixels); splat
// windows reaching image rows 62/63 are clamped into tile row 63 (discarded).

#define WIDTH 60
#define LCURVES 160
#define NSAMP 30
#define NEG_INVA_LOG2E (-7213.4752f)   // -(1/alpha)*log2(e) = -5000*1.442695

typedef _Float16 half8 __attribute__((ext_vector_type(8)));
typedef float floatx4 __attribute__((ext_vector_type(4)));

// Compute splat (chunk CARG, column = lane): bezier point -> window base
// (ni0,nj0) and 12 tap weights in registers (vxs/vys, fully unrolled).
#define COMPUTE_TAPS(CARG)                                                \
    {                                                                     \
        int s = (CARG) * 64 + lane;                                       \
        int l = s % LCURVES;                                              \
        int n = s / LCURVES;                                              \
        const float4* cp = (const float4*)(xb + l * 8);                   \
        float4 c0 = cp[0]; /* x0 y0 x1 y1 */                              \
        float4 c1 = cp[1]; /* x2 y2 x3 y3 */                              \
        float tt = (float)n * (1.0f / NSAMP);                             \
        tt = 2.0f * tt * tt * tt - 3.0f * tt * tt + 2.0f * tt;            \
        float tb = 1.0f - tt, t2 = tt * tt;                               \
        float w0 = t2 * tt;                                               \
        float w1 = 3.0f * (t2 - w0);                                      \
        float w2 = 3.0f * tt * tb * tb;                                   \
        float w3 = tb * tb * tb;                                          \
        float X = w0 * c0.x + w1 * c0.z + w2 * c1.x + w3 * c1.z;          \
        float Y = w0 * c0.y + w1 * c0.w + w2 * c1.y + w3 * c1.w;          \
        ni0 = (int)floorf(X * (float)WIDTH);                              \
        nj0 = (int)floorf(Y * (float)WIDTH);                              \
        ni0 = min(max(ni0, 0), 59);                                       \
        nj0 = min(max(nj0, 0), 59);                                       \
        float bx = (float)(ni0 - 2) * (1.0f / WIDTH) - X;                 \
        float by = (float)(nj0 - 2) * (1.0f / WIDTH) - Y;                 \
        _Pragma("unroll")                                                 \
        for (int a = 0; a < 6; ++a) {                                     \
            float dx = bx + (float)a * (1.0f / WIDTH);                    \
            vxs[a] = __builtin_amdgcn_exp2f(dx * dx * NEG_INVA_LOG2E);    \
            float dy = by + (float)a * (1.0f / WIDTH);                    \
            vys[a] = __builtin_amdgcn_exp2f(dy * dy * NEG_INVA_LOG2E);    \
        }                                                                 \
    }

// Zero the previous chunk's 12 cells (same lane owns the column, in-order DS).
#define ZERO_TAPS()                                                       \
    {                                                                     \
        _Pragma("unroll")                                                 \
        for (int a = 0; a < 6; ++a) {                                     \
            int rz = min(pi0 + a, 63);                                    \
            gx[rz * 64 + (lane ^ ((rz & 7) << 3))] = (_Float16)0;         \
            int rz2 = min(pj0 + a, 63);                                   \
            gy[rz2 * 64 + (lane ^ ((rz2 & 7) << 3))] = (_Float16)0;       \
        }                                                                 \
    }

// Write this chunk's 12 tap weights at (ni0,nj0).
#define WRITE_TAPS()                                                      \
    {                                                                     \
        _Pragma("unroll")                                                 \
        for (int a = 0; a < 6; ++a) {                                     \
            int r = min(ni0 + a, 63);                                     \
            gx[r * 64 + (lane ^ ((r & 7) << 3))] = (_Float16)vxs[a];      \
            int r2 = min(nj0 + a, 63);                                    \
            gy[r2 * 64 + (lane ^ ((r2 & 7) << 3))] = (_Float16)vys[a];    \
        }                                                                 \
    }

__global__ __launch_bounds__(256) void bezier_mfma_kernel(
    const float* __restrict__ x, float* __restrict__ out) {
    // 4 waves x (Gx + Gy) x 64x64 f16 = 65536 B; reused as reduction buffer.
    __shared__ __align__(16) char smem[65536];

    const int tid = threadIdx.x;
    const int lane = tid & 63;
    const int w = tid >> 6;          // wave id 0..3
    const int b = blockIdx.x;
    const int m = lane & 15;         // fragment row/col within 16
    const int q = lane >> 4;         // quad 0..3

    // zero all tiles (4096 float4s)
    float4* sz = (float4*)smem;
#pragma unroll
    for (int i = 0; i < 16; ++i)
        sz[tid + 256 * i] = make_float4(0.f, 0.f, 0.f, 0.f);
    __syncthreads();

    _Float16* gx = (_Float16*)(smem + w * 16384);  // [64 rows][64 cols] swizzled
    _Float16* gy = gx + 4096;

    floatx4 acc[4][4];
#pragma unroll
    for (int ti = 0; ti < 4; ++ti)
#pragma unroll
        for (int tj = 0; tj < 4; ++tj)
            acc[ti][tj] = (floatx4){0.f, 0.f, 0.f, 0.f};

    const float* xb = x + (size_t)b * (LCURVES * 8);

    int pi0, pj0, ni0, nj0;
    float vxs[6], vys[6];

    // Prologue: fill tile for the wave's first chunk (tile is pre-zeroed).
    COMPUTE_TAPS(w);
    WRITE_TAPS();
    pi0 = ni0;
    pj0 = nj0;

    // 75 chunks of 64 splats; wave w owns chunks w, w+4, ... (disjoint K).
    // Pipelined: iteration reads/MFMAs tile cc (written last iteration) and
    // computes+writes tile cc+4.
    for (int cc = w;;) {
        // 1) fragment reads for tile cc: lane(m,q), k = kk*32 + q*8 + j;
        //    swizzled col base = 8*((kk*4+q) ^ (row&7)) -> ds_read_b128.
        half8 af[2][4], bf[2][4];
#pragma unroll
        for (int kk = 0; kk < 2; ++kk)
#pragma unroll
            for (int t = 0; t < 4; ++t) {
                int ra = t * 16 + m;
                af[kk][t] = *(const half8*)&gx[ra * 64 + (((kk * 4 + q) ^ (ra & 7)) << 3)];
                bf[kk][t] = *(const half8*)&gy[ra * 64 + (((kk * 4 + q) ^ (ra & 7)) << 3)];
            }

        int cn = cc + 4;
        bool more = (cn < 75);   // wave-uniform
        // 2) next chunk's VALU (global cp load + bezier + exp2) overlaps the
        //    fragment-read latency; pure register outputs.
        if (more) COMPUTE_TAPS(cn);

        // 3) MFMA tile cc (waits only on the fragment reads).
#pragma unroll
        for (int kk = 0; kk < 2; ++kk)
#pragma unroll
            for (int ti = 0; ti < 4; ++ti)
#pragma unroll
                for (int tj = 0; tj < 4; ++tj)
                    acc[ti][tj] = __builtin_amdgcn_mfma_f32_16x16x32_f16(
                        af[kk][ti], bf[kk][tj], acc[ti][tj], 0, 0, 0);

        if (!more) break;

        // 4) retire tile cc's cells, write tile cn (latency hides under the
        //    next iteration's reads' slack + VALU). Same-wave DS order keeps
        //    these after step-1's reads.
        ZERO_TAPS();
        WRITE_TAPS();
        pi0 = ni0;
        pj0 = nj0;
        cc = cn;
    }

    // Reduce the 4 K-partials. Waves 1..3 park partials in LDS (tile reuse),
    // wave 0 sums + clamps + stores. C/D layout: col=lane&15, row=quad*4+reg.
    __syncthreads();
    if (w > 0) {
        float* red = (float*)smem + (w - 1) * (64 * 65);  // stride 65: no conflicts
#pragma unroll
        for (int ti = 0; ti < 4; ++ti)
#pragma unroll
            for (int tj = 0; tj < 4; ++tj)
#pragma unroll
                for (int r = 0; r < 4; ++r)
                    red[(ti * 16 + q * 4 + r) * 65 + tj * 16 + m] = acc[ti][tj][r];
    }
    __syncthreads();
    if (w == 0) {
        float* r0 = (float*)smem;
        float* r1 = r0 + 64 * 65;
        float* r2 = r1 + 64 * 65;
        float* ob = out + (size_t)b * (WIDTH * WIDTH);
#pragma unroll
        for (int ti = 0; ti < 4; ++ti)
#pragma unroll
            for (int tj = 0; tj < 4; ++tj)
#pragma unroll
                for (int r = 0; r < 4; ++r) {
                    int row = ti * 16 + q * 4 + r;
                    int col = tj * 16 + m;
                    int i = row - 2, j = col - 2;
                    if ((unsigned)i < WIDTH && (unsigned)j < WIDTH) {
                        float v = acc[ti][tj][r] + r0[row * 65 + col] +
                                  r1[row * 65 + col] + r2[row * 65 + col];
                        ob[i * WIDTH + j] = fminf(v, 1.0f);
                    }
                }
    }
}

extern "C" void kernel_launch(void* const* d_in, const int* in_sizes, int n_in,
                              void* d_out, int out_size, void* d_ws, size_t ws_size,
                              hipStream_t stream) {
    const float* x = (const float*)d_in[0];
    float* out = (float*)d_out;
    int B = in_sizes[0] / (LCURVES * 8);  // 256
    bezier_mfma_kernel<<<B, 256, 0, stream>>>(x, out);
}